// Round 10
// baseline (274.362 us; speedup 1.0000x reference)
//
#include <hip/hip_runtime.h>

// SAGEConv x2 forward. Edges bucket-partitioned by dst (256 nodes/bucket).
// agg1 fuses: fine-binning (LDS sort, 2 int LDS-atomics/edge), the xl
// mean-gather, leaky_relu, AND the layer-2 MFMA projection (h lives only in
// an LDS tile -> no h round-trip, no separate gemm2 kernel). gemm1 on MFMA
// with pre-converted bf16 weights; A-tile-only LDS.

constexpr int IN_DIM  = 128;
constexpr int HID     = 64;
constexpr int OUT_DIM = 32;
constexpr float SLOPE = 0.1f;
constexpr int NPB_SHIFT = 8;     // 256 nodes per bucket
constexpr int NBMAX = 512;       // max buckets (N <= 131072)
constexpr int CHUNK = 2048;      // edges per partition block
constexpr int HIST_BLOCKS = 256;
constexpr int SUBCAP = 4096;     // per-half-bucket edge capacity (avg ~2048)

typedef unsigned int uint32;
typedef unsigned short ushort16;

__device__ inline float blo(uint32 u) { return __uint_as_float(u << 16); }
__device__ inline float bhi(uint32 u) { return __uint_as_float(u & 0xffff0000u); }
__device__ inline ushort16 f2b(float f) {
    uint32 u = __float_as_uint(f);
    u += 0x7fffu + ((u >> 16) & 1u);   // round-to-nearest-even
    return (ushort16)(u >> 16);
}
__device__ inline uint32 pack2(float lo, float hi) {
    return (uint32)f2b(lo) | ((uint32)f2b(hi) << 16);
}
__device__ inline float lrelu(float v) { return (v > 0.f) ? v : SLOPE * v; }
__device__ inline void addup(float* acc, uint4 u) {
    acc[0] += blo(u.x); acc[1] += bhi(u.x);
    acc[2] += blo(u.y); acc[3] += bhi(u.y);
    acc[4] += blo(u.z); acc[5] += bhi(u.z);
    acc[6] += blo(u.w); acc[7] += bhi(u.w);
}

// ---- prep: zero bhist + convert weights to bf16 [col][k] layouts ----
__global__ __launch_bounds__(256) void prep_kernel(
    const float* __restrict__ Wl1, const float* __restrict__ Wr1,
    const float* __restrict__ Wl2, const float* __restrict__ Wr2,
    ushort16* __restrict__ Wb1, ushort16* __restrict__ Wb2,
    int* __restrict__ bhist) {
    const int gid = blockIdx.x * 256 + threadIdx.x;
    if (gid < NBMAX) bhist[gid] = 0;
    for (int i = gid; i < 128 * 128; i += gridDim.x * 256) {
        int c = i >> 7, k = i & 127;
        Wb1[i] = f2b((c < HID) ? Wl1[k * HID + c] : Wr1[k * HID + (c - HID)]);
    }
    for (int i = gid; i < 64 * 64; i += gridDim.x * 256) {
        int c = i >> 6, k = i & 63;
        Wb2[i] = f2b((c < OUT_DIM) ? Wl2[k * OUT_DIM + c]
                                   : Wr2[k * OUT_DIM + (c - OUT_DIM)]);
    }
}

// ---- fused: MFMA gemm1 (blocks < ngemm) + bucket histogram (rest) ----
__global__ __launch_bounds__(256) void gemm1_hist_kernel(
    const float* __restrict__ x, const ushort16* __restrict__ Wb1,
    const float* __restrict__ b1,
    const int* __restrict__ dst, int* __restrict__ bhist,
    ushort16* __restrict__ xl, float* __restrict__ xr,
    int N, int E, int ngemm) {
    using frag = __attribute__((ext_vector_type(8))) short;
    using f32x4 = __attribute__((ext_vector_type(4))) float;
    constexpr int LDA = IN_DIM + 8;
    __shared__ ushort16 Ash[64][LDA];               // 17.4 KB
    const int tid = threadIdx.x;
    if (blockIdx.x >= ngemm) {                      // ---- histogram path ----
        int* bh = (int*)Ash;
        for (int i = tid; i < NBMAX; i += 256) bh[i] = 0;
        __syncthreads();
        const int b0 = blockIdx.x - ngemm;
        for (int e = b0 * 256 + tid; e < E; e += HIST_BLOCKS * 256)
            atomicAdd(&bh[dst[e] >> NPB_SHIFT], 1);
        __syncthreads();
        for (int b = tid; b < NBMAX; b += 256)
            if (bh[b]) atomicAdd(&bhist[b], bh[b]);
        return;
    }
    // ---- gemm path ----
    const int n0 = blockIdx.x * 64;
    {
        const int lc = (tid & 31) * 4;
        for (int row = tid >> 5; row < 64; row += 8) {
            int node = n0 + row;
            float4 xv = (node < N)
                ? *reinterpret_cast<const float4*>(&x[(long)node * IN_DIM + lc])
                : float4{0.f, 0.f, 0.f, 0.f};
            ushort16 pk[4] = {f2b(xv.x), f2b(xv.y), f2b(xv.z), f2b(xv.w)};
            *reinterpret_cast<ushort2*>(&Ash[row][lc])     = ushort2{pk[0], pk[1]};
            *reinterpret_cast<ushort2*>(&Ash[row][lc + 2]) = ushort2{pk[2], pk[3]};
        }
    }
    __syncthreads();
    const int lane = tid & 63;
    const int m0   = (tid >> 6) * 16;
    const int mlo  = lane & 15;
    const int qk   = lane >> 4;
    frag Af[4];
#pragma unroll
    for (int kc = 0; kc < 4; ++kc)
        Af[kc] = *reinterpret_cast<const frag*>(&Ash[m0 + mlo][kc * 32 + qk * 8]);
#pragma unroll
    for (int ct = 0; ct < 8; ++ct) {
        f32x4 acc = {0.f, 0.f, 0.f, 0.f};
#pragma unroll
        for (int kc = 0; kc < 4; ++kc) {
            frag Bf = *reinterpret_cast<const frag*>(
                &Wb1[(ct * 16 + mlo) * 128 + kc * 32 + qk * 8]);
            acc = __builtin_amdgcn_mfma_f32_16x16x32_bf16(Af[kc], Bf, acc, 0, 0, 0);
        }
        const int col = ct * 16 + mlo;
#pragma unroll
        for (int r = 0; r < 4; ++r) {
            int node = n0 + m0 + qk * 4 + r;
            if (node < N) {
                if (col < HID) xl[(long)node * HID + col] = f2b(acc[r]);
                else           xr[(long)node * HID + (col - HID)] = acc[r] + b1[col - HID];
            }
        }
    }
}

// ---- scan bucket sizes -> padded pair bases (1 block) ----
__global__ __launch_bounds__(512) void bucket_scan_kernel(
    const int* __restrict__ bhist, int* __restrict__ pbase,
    int* __restrict__ bcur, int NB) {
    __shared__ int s2[512];
    const int t = threadIdx.x;
    int bh = (t < NB) ? bhist[t] : 0;
    int pd = (bh + 15) & ~15;
    s2[t] = pd; __syncthreads();
    for (int off = 1; off < 512; off <<= 1) {
        int b = (t >= off) ? s2[t - off] : 0;
        __syncthreads();
        s2[t] += b;
        __syncthreads();
    }
    pbase[t] = s2[t] - pd;
    bcur[t]  = s2[t] - pd;
}

// ---- partition edges into bucket regions of pairs[] ----
__global__ __launch_bounds__(256) void partition_kernel(
    const int* __restrict__ src, const int* __restrict__ dst,
    int* __restrict__ bcur, uint32* __restrict__ pairs, int E, int NB) {
    __shared__ int hist[NBMAX], loff[NBMAX], cur[NBMAX], gbase[NBMAX];
    __shared__ int s[256];
    __shared__ uint32 stage[CHUNK];
    const int tid = threadIdx.x;
    const int e0  = blockIdx.x * CHUNK;
    const int cnt = min(CHUNK, E - e0);
    for (int i = tid; i < NBMAX; i += 256) hist[i] = 0;
    __syncthreads();
    int sreg[8], dreg[8];
#pragma unroll
    for (int k = 0; k < 8; ++k) {
        int i = tid + k * 256;
        if (i < cnt) {
            sreg[k] = src[e0 + i];
            dreg[k] = dst[e0 + i];
            atomicAdd(&hist[dreg[k] >> NPB_SHIFT], 1);
        }
    }
    __syncthreads();
    int a0 = hist[2 * tid], a1 = hist[2 * tid + 1];
    s[tid] = a0 + a1; __syncthreads();
    for (int off = 1; off < 256; off <<= 1) {
        int t = (tid >= off) ? s[tid - off] : 0;
        __syncthreads();
        s[tid] += t;
        __syncthreads();
    }
    int ex = s[tid] - (a0 + a1);
    loff[2 * tid] = ex;      loff[2 * tid + 1] = ex + a0;
    cur[2 * tid]  = ex;      cur[2 * tid + 1]  = ex + a0;
    __syncthreads();
#pragma unroll
    for (int k = 0; k < 8; ++k) {
        int i = tid + k * 256;
        if (i < cnt) {
            int b = dreg[k] >> NPB_SHIFT;
            int pos = atomicAdd(&cur[b], 1);
            stage[pos] = (uint32)sreg[k] | ((uint32)(dreg[k] & 255) << 24);
        }
    }
    __syncthreads();
    for (int b = tid; b < NB; b += 256) {
        int cb = hist[b];
        if (cb) gbase[b] = atomicAdd(&bcur[b], cb);
    }
    __syncthreads();
    for (int i = tid; i < cnt; i += 256) {
        int lo = 0, hi = NB - 1;
        while (lo < hi) {
            int mid = (lo + hi + 1) >> 1;
            if (loff[mid] <= i) lo = mid; else hi = mid - 1;
        }
        pairs[gbase[lo] + (i - loff[lo])] = stage[i];
    }
}

// ---- agg1 + fine-bin + layer-2 MFMA, all fused ----
// Block = half-bucket (128 nodes), 512 threads. Sorts pairs in LDS, emits
// CSR for agg2, computes h = LR(mean-gather(xl)+xr) into an LDS bf16 tile,
// then MFMA-projects the tile through Wb2 -> hl bf16 / hr fp32 (+b2).
__global__ __launch_bounds__(512) void agg1_fused_kernel(
    const uint32* __restrict__ pairs, const int* __restrict__ bhist,
    const int* __restrict__ pbase,
    const uint4* __restrict__ xlq, const float* __restrict__ xr,
    const ushort16* __restrict__ Wb2, const float* __restrict__ b2,
    uint32* __restrict__ srcs, int* __restrict__ rowptr, int* __restrict__ degA,
    ushort16* __restrict__ hl, float* __restrict__ hr, int N) {
    using frag = __attribute__((ext_vector_type(8))) short;
    using f32x4 = __attribute__((ext_vector_type(4))) float;
    __shared__ int hist[256], loff[256], cur[128];
    __shared__ int lsrc[SUBCAP];
    __shared__ ushort16 hsh[128][72];   // 18.4 KB bf16 h tile (pad 72)
    const int tid  = threadIdx.x;
    const int bkt  = blockIdx.x >> 1;
    const int half = blockIdx.x & 1;
    const int n0   = bkt << NPB_SHIFT;
    const int base = pbase[bkt];
    const int sz   = bhist[bkt];
    if (tid < 256) hist[tid] = 0;
    __syncthreads();
    for (int i = tid; i < sz; i += 512)
        atomicAdd(&hist[pairs[base + i] >> 24], 1);
    __syncthreads();
    int v = (tid < 256) ? hist[tid] : 0;
    if (tid < 256) loff[tid] = v;
    __syncthreads();
    for (int off = 1; off < 256; off <<= 1) {
        int t = (tid >= off && tid < 256) ? loff[tid - off] : 0;
        __syncthreads();
        if (tid < 256) loff[tid] += t;
        __syncthreads();
    }
    if (tid < 256) loff[tid] -= v;                  // exclusive
    __syncthreads();
    if (half == 0 && tid < 256 && n0 + tid < N) {   // CSR for agg2
        rowptr[n0 + tid] = base + loff[tid];
        degA[n0 + tid]   = hist[tid];
    }
    const int hbase = loff[half << 7];
    const int hcnt  = (half ? sz : loff[128]) - hbase;
    if (tid < 128) cur[tid] = loff[(half << 7) + tid] - hbase;
    __syncthreads();
    for (int i = tid; i < sz; i += 512) {           // scatter my half into lsrc
        uint32 u = pairs[base + i];
        int dl = u >> 24;
        if ((dl >> 7) == half) {
            int pos = atomicAdd(&cur[dl & 127], 1);
            lsrc[pos] = (int)(u & 0xFFFFFFu);
        }
    }
    __syncthreads();
    for (int i = tid; i < hcnt; i += 512)           // coalesced CSR srcs
        srcs[base + hbase + i] = (uint32)lsrc[i];
    // ---- gather: 8 lanes/node, 8 nodes/wave, 2 passes of 64 nodes ----
    const int lane = tid & 63;
    const int wid  = tid >> 6;
    const int li   = lane & 7;
#pragma unroll
    for (int pass = 0; pass < 2; ++pass) {
        const int lr = pass * 64 + wid * 8 + (lane >> 3);   // local row 0..127
        const int nl = (half << 7) + lr;
        const int n  = n0 + nl;
        const bool valid = (n < N);
        const int lo0 = loff[nl] - hbase;
        const int d   = valid ? hist[nl] : 0;
        float acc[8] = {};
        int j = 0;
        while (j + 16 <= d) {
            int i0[8], i1[8];
#pragma unroll
            for (int t = 0; t < 8; ++t) i0[t] = lsrc[lo0 + j + t];
#pragma unroll
            for (int t = 0; t < 8; ++t) i1[t] = lsrc[lo0 + j + 8 + t];
            uint4 u0[8], u1[8];
#pragma unroll
            for (int t = 0; t < 8; ++t) u0[t] = xlq[(long)i0[t] * 8 + li];
#pragma unroll
            for (int t = 0; t < 8; ++t) u1[t] = xlq[(long)i1[t] * 8 + li];
#pragma unroll
            for (int t = 0; t < 8; ++t) { addup(acc, u0[t]); addup(acc, u1[t]); }
            j += 16;
        }
        if (j + 8 <= d) {
            int i0[8];
#pragma unroll
            for (int t = 0; t < 8; ++t) i0[t] = lsrc[lo0 + j + t];
            uint4 u0[8];
#pragma unroll
            for (int t = 0; t < 8; ++t) u0[t] = xlq[(long)i0[t] * 8 + li];
#pragma unroll
            for (int t = 0; t < 8; ++t) addup(acc, u0[t]);
            j += 8;
        }
        for (; j < d; ++j) {
            uint4 u = xlq[(long)lsrc[lo0 + j] * 8 + li];
            addup(acc, u);
        }
        const float dinv = (d > 0) ? (1.f / (float)d) : 1.f;
        float4 xrA = {0.f, 0.f, 0.f, 0.f}, xrB = {0.f, 0.f, 0.f, 0.f};
        if (valid) {
            xrA = *reinterpret_cast<const float4*>(&xr[(long)n * HID + 8 * li]);
            xrB = *reinterpret_cast<const float4*>(&xr[(long)n * HID + 8 * li + 4]);
        }
        float h[8];
        h[0] = fmaf(acc[0], dinv, xrA.x); h[1] = fmaf(acc[1], dinv, xrA.y);
        h[2] = fmaf(acc[2], dinv, xrA.z); h[3] = fmaf(acc[3], dinv, xrA.w);
        h[4] = fmaf(acc[4], dinv, xrB.x); h[5] = fmaf(acc[5], dinv, xrB.y);
        h[6] = fmaf(acc[6], dinv, xrB.z); h[7] = fmaf(acc[7], dinv, xrB.w);
#pragma unroll
        for (int t = 0; t < 8; ++t) h[t] = lrelu(h[t]);
        uint4 pk;
        pk.x = pack2(h[0], h[1]); pk.y = pack2(h[2], h[3]);
        pk.z = pack2(h[4], h[5]); pk.w = pack2(h[6], h[7]);
        *reinterpret_cast<uint4*>(&hsh[lr][li * 8]) = pk;   // LDS h tile
    }
    __syncthreads();
    // ---- layer-2 MFMA: hsh[128x64] @ Wb2 -> hl/hr for these 128 nodes ----
    const int m0  = wid * 16;
    const int mlo = lane & 15;
    const int qk  = lane >> 4;
    frag Af[2];
#pragma unroll
    for (int kc = 0; kc < 2; ++kc)
        Af[kc] = *reinterpret_cast<const frag*>(&hsh[m0 + mlo][kc * 32 + qk * 8]);
#pragma unroll
    for (int ct = 0; ct < 4; ++ct) {
        f32x4 acc2 = {0.f, 0.f, 0.f, 0.f};
#pragma unroll
        for (int kc = 0; kc < 2; ++kc) {
            frag Bf = *reinterpret_cast<const frag*>(
                &Wb2[(ct * 16 + mlo) * 64 + kc * 32 + qk * 8]);
            acc2 = __builtin_amdgcn_mfma_f32_16x16x32_bf16(Af[kc], Bf, acc2, 0, 0, 0);
        }
        const int col = ct * 16 + mlo;        // 0..63
#pragma unroll
        for (int r = 0; r < 4; ++r) {
            int node = n0 + (half << 7) + m0 + qk * 4 + r;
            if (node < N) {
                if (col < OUT_DIM) hl[(long)node * OUT_DIM + col] = f2b(acc2[r]);
                else hr[(long)node * OUT_DIM + (col - OUT_DIM)] = acc2[r] + b2[col - OUT_DIM];
            }
        }
    }
}

// ---- agg2: z = LR(mean-gather(hl) + hr) ----
__global__ __launch_bounds__(256) void agg2_final_kernel(
    const int* __restrict__ rowptr, const int* __restrict__ degA,
    const uint32* __restrict__ srcs,
    const uint4* __restrict__ hlq, const float* __restrict__ hr,
    float* __restrict__ z, int N) {
    const int lane  = threadIdx.x & 63;
    const int li    = lane & 3;
    const int gbase = lane & 60;
    const int wave  = (blockIdx.x << 2) + (threadIdx.x >> 6);
    const int n     = wave * 16 + (lane >> 2);
    if (n >= N) return;
    const int rp = rowptr[n];
    const int d  = degA[n];
    float acc[8] = {};
    int j = 0;
    while (j + 16 <= d) {
        int sA = (int)srcs[rp + j + li];
        int sB = (int)srcs[rp + j + 4 + li];
        int sC = (int)srcs[rp + j + 8 + li];
        int sD = (int)srcs[rp + j + 12 + li];
        uint4 u[16];
#pragma unroll
        for (int t = 0; t < 4; ++t) u[t]      = hlq[(long)__shfl(sA, gbase + t) * 4 + li];
#pragma unroll
        for (int t = 0; t < 4; ++t) u[4 + t]  = hlq[(long)__shfl(sB, gbase + t) * 4 + li];
#pragma unroll
        for (int t = 0; t < 4; ++t) u[8 + t]  = hlq[(long)__shfl(sC, gbase + t) * 4 + li];
#pragma unroll
        for (int t = 0; t < 4; ++t) u[12 + t] = hlq[(long)__shfl(sD, gbase + t) * 4 + li];
#pragma unroll
        for (int t = 0; t < 16; ++t) addup(acc, u[t]);
        j += 16;
    }
    while (j + 4 <= d) {
        int sA = (int)srcs[rp + j + li];
        uint4 u[4];
#pragma unroll
        for (int t = 0; t < 4; ++t) u[t] = hlq[(long)__shfl(sA, gbase + t) * 4 + li];
#pragma unroll
        for (int t = 0; t < 4; ++t) addup(acc, u[t]);
        j += 4;
    }
    int r = d - j;                     // 0..3
    if (r > 0) {
        int sA = (int)srcs[rp + j + ((li < r) ? li : 0)];
#pragma unroll
        for (int t = 0; t < 3; ++t) {
            if (t < r) {
                uint4 u = hlq[(long)__shfl(sA, gbase + t) * 4 + li];
                addup(acc, u);
            }
        }
    }
    const float dinv = (d > 0) ? (1.f / (float)d) : 1.f;
    float4 hA = *reinterpret_cast<const float4*>(&hr[(long)n * OUT_DIM + 8 * li]);
    float4 hB = *reinterpret_cast<const float4*>(&hr[(long)n * OUT_DIM + 8 * li + 4]);
    float4 vA, vB;
    vA.x = lrelu(fmaf(acc[0], dinv, hA.x)); vA.y = lrelu(fmaf(acc[1], dinv, hA.y));
    vA.z = lrelu(fmaf(acc[2], dinv, hA.z)); vA.w = lrelu(fmaf(acc[3], dinv, hA.w));
    vB.x = lrelu(fmaf(acc[4], dinv, hB.x)); vB.y = lrelu(fmaf(acc[5], dinv, hB.y));
    vB.z = lrelu(fmaf(acc[6], dinv, hB.z)); vB.w = lrelu(fmaf(acc[7], dinv, hB.w));
    *reinterpret_cast<float4*>(&z[(long)n * OUT_DIM + 8 * li]) = vA;
    *reinterpret_cast<float4*>(&z[(long)n * OUT_DIM + 8 * li + 4]) = vB;
}

extern "C" void kernel_launch(void* const* d_in, const int* in_sizes, int n_in,
                              void* d_out, int out_size, void* d_ws, size_t ws_size,
                              hipStream_t stream) {
    const float* x   = (const float*)d_in[0];
    const int*   ei  = (const int*)d_in[1];
    const float* Wl1 = (const float*)d_in[2];
    const float* Wr1 = (const float*)d_in[3];
    const float* b1  = (const float*)d_in[4];
    const float* Wl2 = (const float*)d_in[5];
    const float* Wr2 = (const float*)d_in[6];
    const float* b2  = (const float*)d_in[7];

    const int N = in_sizes[0] / IN_DIM;
    const int E = in_sizes[1] / 2;
    const int* src = ei;
    const int* dst = ei + E;
    const int NB = (N + 255) >> NPB_SHIFT;   // buckets (<= 512)

    char* p = (char*)d_ws;
    int* bhist    = (int*)p;           p += sizeof(int) * NBMAX;
    int* pbase    = (int*)p;           p += sizeof(int) * NBMAX;
    int* bcur     = (int*)p;           p += sizeof(int) * NBMAX;
    int* rowptr   = (int*)p;           p += sizeof(int) * (N + 4);
    int* degA     = (int*)p;           p += sizeof(int) * (N + 4);
    uint32* pairs = (uint32*)p;        p += sizeof(uint32) * ((size_t)E + 16 * NBMAX);
    uint32* srcs  = (uint32*)p;        p += sizeof(uint32) * ((size_t)E + 16 * NBMAX);
    ushort16* Wb1 = (ushort16*)p;      p += sizeof(ushort16) * 128 * 128;
    ushort16* Wb2 = (ushort16*)p;      p += sizeof(ushort16) * 64 * 64;
    ushort16* xl  = (ushort16*)p;      p += sizeof(ushort16) * (size_t)N * HID;
    float* xr     = (float*)p;         p += sizeof(float) * (size_t)N * HID;
    ushort16* hl  = (ushort16*)p;      p += sizeof(ushort16) * (size_t)N * OUT_DIM;
    float* hr     = (float*)p;         p += sizeof(float) * (size_t)N * OUT_DIM;

    const int ngemm = (N + 63) / 64;
    prep_kernel<<<32, 256, 0, stream>>>(Wl1, Wr1, Wl2, Wr2, Wb1, Wb2, bhist);
    gemm1_hist_kernel<<<ngemm + HIST_BLOCKS, 256, 0, stream>>>(
        x, Wb1, b1, dst, bhist, xl, xr, N, E, ngemm);
    bucket_scan_kernel<<<1, 512, 0, stream>>>(bhist, pbase, bcur, NB);
    partition_kernel<<<(E + CHUNK - 1) / CHUNK, 256, 0, stream>>>(src, dst, bcur, pairs, E, NB);
    agg1_fused_kernel<<<NB * 2, 512, 0, stream>>>(pairs, bhist, pbase,
                                                  (const uint4*)xl, xr, Wb2, b2,
                                                  srcs, rowptr, degA, hl, hr, N);
    agg2_final_kernel<<<(N + 63) / 64, 256, 0, stream>>>(rowptr, degA, srcs,
                                                         (const uint4*)hl, hr,
                                                         (float*)d_out, N);
}